// Round 11
// baseline (372.636 us; speedup 1.0000x reference)
//
#include <hip/hip_runtime.h>
#include <hip/hip_bf16.h>

// ---------------- problem dims ----------------
#define D_MODEL 1024
#define D_INNER 2048
#define D_STATE 16
#define D_CONVK 4
#define DT_RANK 64
#define BATCH   2
#define SEQ     1024
#define NROWS   (BATCH*SEQ)          // 2048 rows (b*s flattened)

// scan chunking (chain-per-lane layout)
#define NCHUNK  32
#define CHUNK   (SEQ/NCHUNK)         // 32

// ---------------- ws layout (float elements) ----------------
#define XZ_OFF  0
#define XZ_SZ   (NROWS*2*D_INNER)
#define XC_OFF  (XZ_OFF + XZ_SZ)
#define XC_SZ   (NROWS*D_INNER)
#define DBL_OFF (XC_OFF + XC_SZ)
#define DBL_SZ  (NROWS*96)
#define DT_OFF  (DBL_OFF + DBL_SZ)
#define DT_SZ   (NROWS*D_INNER)
#define YG_OFF  (DT_OFF + DT_SZ)
#define YG_SZ   (NROWS*D_INNER)
// total = 21,168,128 floats = 84.7 MB (unchanged)
//
// Region reuse timeline (write-before-read everywhere):
//  yg region: [t0] xb bf16 | W_in_b bf16 (dead after in_proj)
//             [scanA/B] Pbuf | Lbuf (dead after scanB) -> [scanC] yg f32
//  dt region: [xproj] partials -> [dtproj] dt f32
//             [after scanC] ygb bf16 | W_out_b bf16
//  xc region: conv output; dead after scanC -> out_proj split-K partials (2x2M)
//  xz x_in half: dead after conv -> HST

// HST packed into the x_in half of xz (row stride 4096)
__device__ __forceinline__ float& plh_at(float* xz, int i) {
  return xz[((size_t)(i >> 11)) * (2 * D_INNER) + (i & (D_INNER - 1))];
}

typedef unsigned short ushort_t;
typedef __attribute__((ext_vector_type(8))) short  bf16x8;
typedef __attribute__((ext_vector_type(4))) float  f32x4;

__device__ __forceinline__ ushort_t f2bf(float f) {
  unsigned u = __float_as_uint(f);
  unsigned r = (u + 0x7fffu + ((u >> 16) & 1u)) >> 16;
  return (ushort_t)r;
}

__device__ __forceinline__ void gld_lds16(const ushort_t* g, ushort_t* l) {
  __builtin_amdgcn_global_load_lds(
      (const __attribute__((address_space(1))) unsigned int*)(const void*)g,
      (__attribute__((address_space(3))) unsigned int*)(void*)l,
      16, 0, 0);
}

// ======================================================================
// f32 -> bf16 convert
// ======================================================================
__global__ __launch_bounds__(256) void f32_to_bf16_kernel(
    const float* __restrict__ src, ushort_t* __restrict__ dst, int n4)
{
  const int i = blockIdx.x * 256 + threadIdx.x;
  if (i >= n4) return;
  const float4 v = ((const float4*)src)[i];
  ushort4 o;
  o.x = f2bf(v.x); o.y = f2bf(v.y); o.z = f2bf(v.z); o.w = f2bf(v.w);
  ((ushort4*)dst)[i] = o;
}

// ======================================================================
// Single-wave bf16 MFMA GEMM, depth-2 pipelined.
// One 64-thread wave per block owns a 64x64 tile (4x4 frags of 16x16x32).
// BK=32, double-buffered LDS, global_load_lds staging with bank-conflict
// swizzle (linear LDS dest, pre-swizzled global source). NO barriers:
// single wave; counted s_waitcnt vmcnt(8) keeps next tile's 8 loads in
// flight while computing current (T3/T4 minimal form; rule #18 fence).
// WAR safety: iter k's ds_reads are lgkm-drained before its MFMAs (compiler
// inserts lgkmcnt before use), which precede iter k+2's overwriting loads
// in program order; DMA writes land after.
// Optional split-K via blockIdx.z: C slice z at C + z*(gridDim.y*64)*ldc.
// ======================================================================
#define DEF_GEMM_WAVE(NAME)                                                    \
__global__ __launch_bounds__(64, 4) void NAME(                                 \
    const ushort_t* __restrict__ A, int lda,                                   \
    const ushort_t* __restrict__ B, int ldb,                                   \
    float* __restrict__ C, int ldc, int klen)                                  \
{                                                                              \
  __shared__ __attribute__((aligned(16))) ushort_t As[2][64 * 32];             \
  __shared__ __attribute__((aligned(16))) ushort_t Bs[2][64 * 32];             \
                                                                               \
  const int l  = threadIdx.x;                                                  \
  const int lm = l & 15;                                                       \
  const int lk = l >> 4;                                                       \
  const int bn = blockIdx.x * 64;                                              \
  const int bm = blockIdx.y * 64;                                              \
  const int kbase = blockIdx.z * klen;                                         \
  float* Cz = C + (size_t)blockIdx.z * (size_t)gridDim.y * 64 * ldc;           \
                                                                               \
  const int srow  = l >> 2;                                                    \
  const int scol  = ((l & 3) ^ ((l >> 3) & 3)) * 8;                            \
  const int rslot = (lk ^ ((lm >> 1) & 3)) * 8;                                \
                                                                               \
  f32x4 acc[4][4];                                                             \
  _Pragma("unroll")                                                            \
  for (int i = 0; i < 4; ++i)                                                  \
    _Pragma("unroll")                                                          \
    for (int j = 0; j < 4; ++j) acc[i][j] = (f32x4){0.f, 0.f, 0.f, 0.f};       \
                                                                               \
  const int nk = klen >> 5;                                                    \
  /* prologue: stage tile 0 into buf 0 */                                      \
  _Pragma("unroll")                                                            \
  for (int i = 0; i < 4; ++i) {                                                \
    gld_lds16(A + (size_t)(bm + i * 16 + srow) * lda + kbase + scol,           \
              &As[0][i * 16 * 32]);                                            \
    gld_lds16(B + (size_t)(bn + i * 16 + srow) * ldb + kbase + scol,           \
              &Bs[0][i * 16 * 32]);                                            \
  }                                                                            \
                                                                               \
  for (int k = 0; k < nk; ++k) {                                               \
    const int cur = k & 1;                                                     \
    if (k + 1 < nk) {                                                          \
      const int nxt = cur ^ 1;                                                 \
      const int k1 = kbase + (k + 1) * 32;                                     \
      _Pragma("unroll")                                                        \
      for (int i = 0; i < 4; ++i) {                                            \
        gld_lds16(A + (size_t)(bm + i * 16 + srow) * lda + k1 + scol,          \
                  &As[nxt][i * 16 * 32]);                                      \
        gld_lds16(B + (size_t)(bn + i * 16 + srow) * ldb + k1 + scol,          \
                  &Bs[nxt][i * 16 * 32]);                                      \
      }                                                                        \
      asm volatile("s_waitcnt vmcnt(8)" ::: "memory");                         \
    } else {                                                                   \
      asm volatile("s_waitcnt vmcnt(0)" ::: "memory");                         \
    }                                                                          \
    __builtin_amdgcn_sched_barrier(0);                                         \
                                                                               \
    bf16x8 af[4], bf[4];                                                       \
    _Pragma("unroll")                                                          \
    for (int mi = 0; mi < 4; ++mi)                                             \
      af[mi] = *(const bf16x8*)&As[cur][(mi * 16 + lm) * 32 + rslot];          \
    _Pragma("unroll")                                                          \
    for (int ni = 0; ni < 4; ++ni)                                             \
      bf[ni] = *(const bf16x8*)&Bs[cur][(ni * 16 + lm) * 32 + rslot];          \
    _Pragma("unroll")                                                          \
    for (int mi = 0; mi < 4; ++mi)                                             \
      _Pragma("unroll")                                                        \
      for (int ni = 0; ni < 4; ++ni)                                           \
        acc[mi][ni] = __builtin_amdgcn_mfma_f32_16x16x32_bf16(                 \
            af[mi], bf[ni], acc[mi][ni], 0, 0, 0);                             \
  }                                                                            \
                                                                               \
  _Pragma("unroll")                                                            \
  for (int mi = 0; mi < 4; ++mi) {                                             \
    _Pragma("unroll")                                                          \
    for (int ni = 0; ni < 4; ++ni) {                                           \
      const f32x4 v = acc[mi][ni];                                             \
      const int row0 = bm + mi * 16 + lk * 4;                                  \
      const int col  = bn + ni * 16 + lm;                                      \
      _Pragma("unroll")                                                        \
      for (int r = 0; r < 4; ++r)                                              \
        Cz[(size_t)(row0 + r) * ldc + col] = v[r];                             \
    }                                                                          \
  }                                                                            \
}

DEF_GEMM_WAVE(gemm_wave_in)
DEF_GEMM_WAVE(gemm_wave_out)

// out = p0 + p1 over NROWS*D_MODEL (split-K=2 reduce for out_proj)
__global__ __launch_bounds__(256) void splitk2_reduce_kernel(
    const float* __restrict__ part, float* __restrict__ out)
{
  const int i = blockIdx.x * 256 + threadIdx.x;   // over NROWS*D_MODEL/4
  const float4 a = ((const float4*)part)[i];
  const float4 b = ((const float4*)part)[i + (NROWS * D_MODEL / 4)];
  ((float4*)out)[i] = make_float4(a.x + b.x, a.y + b.y, a.z + b.z, a.w + b.w);
}

// ======================================================================
// x_proj split-K, dense partials (no atomics)
// ======================================================================
#define XP_NS 16
#define XP_KC (D_INNER / XP_NS)   // 128
#define XP_BK 16

__global__ __launch_bounds__(256) void xproj_part_kernel(
    const float* __restrict__ A,   // xc [2048][2048]
    const float* __restrict__ B,   // W_x [96][2048]
    float* __restrict__ part)      // [16][2048][96]
{
  __shared__ float As[XP_BK][64 + 4];
  __shared__ float Bs[XP_BK][96 + 4];

  const int tid = threadIdx.x;
  const int bm = blockIdx.x * 64;
  const int kbase = blockIdx.y * XP_KC;
  const int tm = tid >> 4;
  const int tn = tid & 15;

  float acc[4][6];
#pragma unroll
  for (int i = 0; i < 4; ++i)
#pragma unroll
    for (int j = 0; j < 6; ++j) acc[i][j] = 0.f;

  for (int k0 = kbase; k0 < kbase + XP_KC; k0 += XP_BK) {
    {
      const int row = tid >> 2, kc = (tid & 3) * 4;
      const float4 v = *(const float4*)(A + (size_t)(bm + row) * D_INNER + k0 + kc);
      As[kc + 0][row] = v.x; As[kc + 1][row] = v.y;
      As[kc + 2][row] = v.z; As[kc + 3][row] = v.w;
    }
    for (int idx = tid; idx < 96 * 4; idx += 256) {
      const int row = idx >> 2, kc = (idx & 3) * 4;
      const float4 v = *(const float4*)(B + (size_t)row * D_INNER + k0 + kc);
      Bs[kc + 0][row] = v.x; Bs[kc + 1][row] = v.y;
      Bs[kc + 2][row] = v.z; Bs[kc + 3][row] = v.w;
    }
    __syncthreads();

#pragma unroll
    for (int kk = 0; kk < XP_BK; ++kk) {
      float a[4], b[6];
#pragma unroll
      for (int i = 0; i < 4; ++i) a[i] = As[kk][tm * 4 + i];
#pragma unroll
      for (int j = 0; j < 6; ++j) b[j] = Bs[kk][tn * 6 + j];
#pragma unroll
      for (int i = 0; i < 4; ++i)
#pragma unroll
        for (int j = 0; j < 6; ++j)
          acc[i][j] = fmaf(a[i], b[j], acc[i][j]);
    }
    __syncthreads();
  }

  float* p = part + (size_t)blockIdx.y * (NROWS * 96);
#pragma unroll
  for (int i = 0; i < 4; ++i) {
    const int gm = bm + tm * 4 + i;
#pragma unroll
    for (int j = 0; j < 6; ++j)
      p[(size_t)gm * 96 + tn * 6 + j] = acc[i][j];
  }
}

__global__ __launch_bounds__(256) void xproj_reduce_kernel(
    const float* __restrict__ part, float* __restrict__ dbl)
{
  const int i = blockIdx.x * 256 + threadIdx.x;
  const float4* p4 = (const float4*)part;
  float4 s = p4[i];
#pragma unroll
  for (int ks = 1; ks < XP_NS; ++ks) {
    const float4 v = p4[(size_t)ks * (NROWS * 96 / 4) + i];
    s.x += v.x; s.y += v.y; s.z += v.z; s.w += v.w;
  }
  ((float4*)dbl)[i] = s;
}

// ======================================================================
// dt_proj + fused softplus
// ======================================================================
__global__ __launch_bounds__(256) void dtproj_kernel(
    const float* __restrict__ A,    // dbl [2048][96] (cols 0..63)
    const float* __restrict__ B,    // W_dt [2048][64]
    const float* __restrict__ b_dt,
    float* __restrict__ C)          // dt [2048][2048]
{
  __shared__ float As[16][128 + 4];
  __shared__ float Bs[16][128 + 4];

  const int tid = threadIdx.x;
  const int bm = blockIdx.y * 128;
  const int bn = blockIdx.x * 128;
  const int tm = tid >> 4;
  const int tn = tid & 15;

  float acc[8][8];
#pragma unroll
  for (int i = 0; i < 8; ++i)
#pragma unroll
    for (int j = 0; j < 8; ++j) acc[i][j] = 0.f;

  for (int k0 = 0; k0 < DT_RANK; k0 += 16) {
    for (int idx = tid; idx < 512; idx += 256) {
      const int row = idx >> 2, kc = (idx & 3) * 4;
      {
        const float4 v = *(const float4*)(A + (size_t)(bm + row) * 96 + k0 + kc);
        As[kc + 0][row] = v.x; As[kc + 1][row] = v.y;
        As[kc + 2][row] = v.z; As[kc + 3][row] = v.w;
      }
      {
        const float4 v = *(const float4*)(B + (size_t)(bn + row) * DT_RANK + k0 + kc);
        Bs[kc + 0][row] = v.x; Bs[kc + 1][row] = v.y;
        Bs[kc + 2][row] = v.z; Bs[kc + 3][row] = v.w;
      }
    }
    __syncthreads();

#pragma unroll
    for (int kk = 0; kk < 16; ++kk) {
      const float4 a0 = *(const float4*)&As[kk][tm * 8];
      const float4 a1 = *(const float4*)&As[kk][tm * 8 + 4];
      const float4 b0 = *(const float4*)&Bs[kk][tn * 8];
      const float4 b1 = *(const float4*)&Bs[kk][tn * 8 + 4];
      const float a[8] = {a0.x,a0.y,a0.z,a0.w,a1.x,a1.y,a1.z,a1.w};
      const float b[8] = {b0.x,b0.y,b0.z,b0.w,b1.x,b1.y,b1.z,b1.w};
#pragma unroll
      for (int i = 0; i < 8; ++i)
#pragma unroll
        for (int j = 0; j < 8; ++j)
          acc[i][j] = fmaf(a[i], b[j], acc[i][j]);
    }
    __syncthreads();
  }

  const int gn0 = bn + tn * 8;
  float bv[8];
#pragma unroll
  for (int j = 0; j < 8; ++j) bv[j] = b_dt[gn0 + j];
#pragma unroll
  for (int i = 0; i < 8; ++i) {
    const int gm = bm + tm * 8 + i;
    float o[8];
#pragma unroll
    for (int j = 0; j < 8; ++j) {
      const float v = acc[i][j] + bv[j];
      const float sp = (v > 20.f) ? v : log1pf(__expf(v));
      o[j] = sp + 1e-4f;
    }
    *(float4*)(C + (size_t)gm * D_INNER + gn0)     = make_float4(o[0], o[1], o[2], o[3]);
    *(float4*)(C + (size_t)gm * D_INNER + gn0 + 4) = make_float4(o[4], o[5], o[6], o[7]);
  }
}

// ======================================================================
// depthwise causal conv1d + SiLU
// ======================================================================
__global__ __launch_bounds__(256) void conv_silu_kernel(
    const float* __restrict__ xz, const float* __restrict__ Wc,
    const float* __restrict__ bc, float* __restrict__ xc)
{
  const int idx = blockIdx.x * 256 + threadIdx.x;
  const int d = idx & (D_INNER - 1);
  const int m = idx >> 11;
  const int s = m & (SEQ - 1);
  const int mb = m - s;
  float acc = bc[d];
#pragma unroll
  for (int k = 0; k < D_CONVK; ++k) {
    const int t = s + k - (D_CONVK - 1);
    if (t >= 0)
      acc = fmaf(Wc[d * D_CONVK + k], xz[(size_t)(mb + t) * (2 * D_INNER) + d], acc);
  }
  xc[idx] = acc / (1.f + __expf(-acc));
}

// ======================================================================
// scan pass A (chain-per-lane)
// ======================================================================
__global__ __launch_bounds__(256) void scanA_kernel(
    const float* __restrict__ dtv, const float* __restrict__ xc,
    const float* __restrict__ dbl, const float* __restrict__ A_log,
    float* __restrict__ Pbuf, float* __restrict__ Lbuf)
{
  __shared__ float sB[CHUNK][16];

  const int tid = threadIdx.x;
  const int d = blockIdx.x * 256 + tid;
  const int chunk = blockIdx.y;
  const int b = blockIdx.z;
  const int rowbase = b * SEQ + chunk * CHUNK;

  for (int idx = tid; idx < CHUNK * 16; idx += 256) {
    const int i = idx >> 4, n = idx & 15;
    sB[i][n] = dbl[(size_t)(rowbase + i) * 96 + 64 + n];
  }

  float A_d[16];
#pragma unroll
  for (int j = 0; j < 4; ++j) {
    const float4 va = *(const float4*)&A_log[d * D_STATE + j * 4];
    A_d[j * 4 + 0] = -__expf(va.x);
    A_d[j * 4 + 1] = -__expf(va.y);
    A_d[j * 4 + 2] = -__expf(va.z);
    A_d[j * 4 + 3] = -__expf(va.w);
  }
  __syncthreads();

  float h[16], P[16];
#pragma unroll
  for (int n = 0; n < 16; ++n) { h[n] = 0.f; P[n] = 1.f; }

  for (int i = 0; i < CHUNK; ++i) {
    const size_t off = (size_t)(rowbase + i) * D_INNER + d;
    const float dt_v = dtv[off];
    const float dtxc = dt_v * xc[off];
    const float4 B0 = *(const float4*)&sB[i][0];
    const float4 B1 = *(const float4*)&sB[i][4];
    const float4 B2 = *(const float4*)&sB[i][8];
    const float4 B3 = *(const float4*)&sB[i][12];
    const float Bv[16] = {B0.x,B0.y,B0.z,B0.w, B1.x,B1.y,B1.z,B1.w,
                          B2.x,B2.y,B2.z,B2.w, B3.x,B3.y,B3.z,B3.w};
#pragma unroll
    for (int n = 0; n < 16; ++n) {
      float t = dt_v * A_d[n];
      t = fminf(fmaxf(t, -10.f), 10.f);
      const float dA = __expf(t);
      h[n] = fmaf(dA, h[n], dtxc * Bv[n]);
      P[n] *= dA;
    }
  }

  const size_t base = ((size_t)(chunk * BATCH + b) * 16) * D_INNER + d;
#pragma unroll
  for (int n = 0; n < 16; ++n) {
    Pbuf[base + (size_t)n * D_INNER] = P[n];
    Lbuf[base + (size_t)n * D_INNER] = h[n];
  }
}

// ======================================================================
// scan pass B
// ======================================================================
__global__ __launch_bounds__(256) void scanB_kernel(
    const float* __restrict__ Pbuf, const float* __restrict__ Lbuf,
    float* __restrict__ xzp)
{
  const int t = blockIdx.x * 256 + threadIdx.x;
  const int d = t & (D_INNER - 1);
  const int n = (t >> 11) & 15;
  const int b = t >> 15;
  float hs = 0.f;
#pragma unroll
  for (int c = 0; c < NCHUNK; ++c) {
    const int idx = ((c * BATCH + b) * 16 + n) * D_INNER + d;
    plh_at(xzp, idx) = hs;
    hs = fmaf(Pbuf[idx], hs, Lbuf[idx]);
  }
}

// ======================================================================
// scan pass C (chain-per-lane)
// ======================================================================
__global__ __launch_bounds__(256) void scanC_kernel(
    const float* __restrict__ dtv, const float* __restrict__ xc,
    const float* __restrict__ dbl, const float* __restrict__ A_log,
    const float* __restrict__ Dp,  float* __restrict__ xzp,
    float* __restrict__ yg)
{
  __shared__ float sBC[CHUNK][32];

  const int tid = threadIdx.x;
  const int d = blockIdx.x * 256 + tid;
  const int chunk = blockIdx.y;
  const int b = blockIdx.z;
  const int rowbase = b * SEQ + chunk * CHUNK;

  for (int idx = tid; idx < CHUNK * 32; idx += 256) {
    const int i = idx >> 5, j = idx & 31;
    sBC[i][j] = dbl[(size_t)(rowbase + i) * 96 + 64 + j];
  }

  float A_d[16];
#pragma unroll
  for (int j = 0; j < 4; ++j) {
    const float4 va = *(const float4*)&A_log[d * D_STATE + j * 4];
    A_d[j * 4 + 0] = -__expf(va.x);
    A_d[j * 4 + 1] = -__expf(va.y);
    A_d[j * 4 + 2] = -__expf(va.z);
    A_d[j * 4 + 3] = -__expf(va.w);
  }
  const float Dd = Dp[d];
  __syncthreads();

  float h[16];
  {
    const int hbase = ((chunk * BATCH + b) * 16) * D_INNER + d;
#pragma unroll
    for (int n = 0; n < 16; ++n) h[n] = plh_at(xzp, hbase + n * D_INNER);
  }

  for (int i = 0; i < CHUNK; ++i) {
    const int m = rowbase + i;
    const size_t off = (size_t)m * D_INNER + d;
    const float dt_v = dtv[off];
    const float xc_v = xc[off];
    const float dtxc = dt_v * xc_v;
    const float4 B0 = *(const float4*)&sBC[i][0];
    const float4 B1 = *(const float4*)&sBC[i][4];
    const float4 B2 = *(const float4*)&sBC[i][8];
    const float4 B3 = *(const float4*)&sBC[i][12];
    const float4 C0 = *(const float4*)&sBC[i][16];
    const float4 C1 = *(const float4*)&sBC[i][20];
    const float4 C2 = *(const float4*)&sBC[i][24];
    const float4 C3 = *(const float4*)&sBC[i][28];
    const float Bv[16] = {B0.x,B0.y,B0.z,B0.w, B1.x,B1.y,B1.z,B1.w,
                          B2.x,B2.y,B2.z,B2.w, B3.x,B3.y,B3.z,B3.w};
    const float Cv[16] = {C0.x,C0.y,C0.z,C0.w, C1.x,C1.y,C1.z,C1.w,
                          C2.x,C2.y,C2.z,C2.w, C3.x,C3.y,C3.z,C3.w};
    float y = 0.f;
#pragma unroll
    for (int n = 0; n < 16; ++n) {
      float t = dt_v * A_d[n];
      t = fminf(fmaxf(t, -10.f), 10.f);
      const float dA = __expf(t);
      h[n] = fmaf(dA, h[n], dtxc * Bv[n]);
      y = fmaf(h[n], Cv[n], y);
    }
    const float zv = xzp[(size_t)m * (2 * D_INNER) + D_INNER + d];
    const float sil = zv / (1.f + __expf(-zv));
    yg[off] = (y + xc_v * Dd) * sil;
  }
}

// ======================================================================
// RMSNorm: read yg f32, write bf16
// ======================================================================
__global__ __launch_bounds__(256) void rms_bf16_kernel(
    const float* __restrict__ yg, const float* __restrict__ rms_w,
    ushort_t* __restrict__ ygb)
{
  const int m = blockIdx.x;
  const float* row = yg + (size_t)m * D_INNER;
  const int e0 = threadIdx.x * 8;
  float4 v0 = *(const float4*)&row[e0];
  float4 v1 = *(const float4*)&row[e0 + 4];
  float ss = v0.x*v0.x + v0.y*v0.y + v0.z*v0.z + v0.w*v0.w
           + v1.x*v1.x + v1.y*v1.y + v1.z*v1.z + v1.w*v1.w;
#pragma unroll
  for (int off = 32; off > 0; off >>= 1) ss += __shfl_down(ss, off);
  __shared__ float wsum[4];
  const int lane = threadIdx.x & 63, wid = threadIdx.x >> 6;
  if (lane == 0) wsum[wid] = ss;
  __syncthreads();
  const float total = wsum[0] + wsum[1] + wsum[2] + wsum[3];
  const float scale = rsqrtf(total / (float)D_INNER + 1e-6f);
  const float4 w0 = *(const float4*)&rms_w[e0];
  const float4 w1 = *(const float4*)&rms_w[e0 + 4];
  ushort4 o0, o1;
  o0.x = f2bf(v0.x * scale * w0.x); o0.y = f2bf(v0.y * scale * w0.y);
  o0.z = f2bf(v0.z * scale * w0.z); o0.w = f2bf(v0.w * scale * w0.w);
  o1.x = f2bf(v1.x * scale * w1.x); o1.y = f2bf(v1.y * scale * w1.y);
  o1.z = f2bf(v1.z * scale * w1.z); o1.w = f2bf(v1.w * scale * w1.w);
  *(ushort4*)&ygb[(size_t)m * D_INNER + e0]     = o0;
  *(ushort4*)&ygb[(size_t)m * D_INNER + e0 + 4] = o1;
}

// ======================================================================
extern "C" void kernel_launch(void* const* d_in, const int* in_sizes, int n_in,
                              void* d_out, int out_size, void* d_ws, size_t ws_size,
                              hipStream_t stream) {
  const float* x      = (const float*)d_in[0];
  const float* W_in   = (const float*)d_in[1];
  const float* W_conv = (const float*)d_in[2];
  const float* b_conv = (const float*)d_in[3];
  const float* W_x    = (const float*)d_in[4];
  const float* W_dt   = (const float*)d_in[5];
  const float* b_dt   = (const float*)d_in[6];
  const float* A_log  = (const float*)d_in[7];
  const float* Dp     = (const float*)d_in[8];
  const float* rms_w  = (const float*)d_in[9];
  const float* W_out  = (const float*)d_in[10];
  float* out = (float*)d_out;
  float* ws  = (float*)d_ws;

  float* xz  = ws + XZ_OFF;
  float* xc  = ws + XC_OFF;
  float* dbl = ws + DBL_OFF;
  float* dt  = ws + DT_OFF;
  float* yg  = ws + YG_OFF;

  // region-reuse aliases
  ushort_t* xb      = (ushort_t*)(ws + YG_OFF);                    // bf16 x
  ushort_t* W_in_b  = (ushort_t*)(ws + YG_OFF + 1024 * 1024);      // bf16 W_in
  float*    xpart   = ws + DT_OFF;                                 // xproj partials
  float*    Pbuf    = ws + YG_OFF;                                 // scan P
  float*    Lbuf    = ws + YG_OFF + 2 * 1024 * 1024;               // scan L
  ushort_t* ygb     = (ushort_t*)(ws + DT_OFF);                    // bf16 y
  ushort_t* W_out_b = (ushort_t*)(ws + DT_OFF + 2 * 1024 * 1024);  // bf16 W_out
  float*    opart   = ws + XC_OFF;                                 // out_proj partials (2x2M, xc dead)

  // 0. convert x, W_in to bf16
  f32_to_bf16_kernel<<<(NROWS * D_MODEL / 4 + 255) / 256, 256, 0, stream>>>(x, xb, NROWS * D_MODEL / 4);
  f32_to_bf16_kernel<<<(2 * D_INNER * D_MODEL / 4 + 255) / 256, 256, 0, stream>>>(W_in, W_in_b, 2 * D_INNER * D_MODEL / 4);

  // 1. in_proj: xz = xb @ W_in_b^T (single-wave pipelined MFMA, 2048 blocks)
  {
    dim3 g((2 * D_INNER) / 64, NROWS / 64, 1);
    gemm_wave_in<<<g, 64, 0, stream>>>(xb, D_MODEL, W_in_b, D_MODEL, xz, 2 * D_INNER, D_MODEL);
  }
  // 2. conv + silu -> xc
  conv_silu_kernel<<<(NROWS * D_INNER) / 256, 256, 0, stream>>>(xz, W_conv, b_conv, xc);
  // 3. x_proj: dense split-K partials + reduce
  {
    dim3 g(NROWS / 64, XP_NS);
    xproj_part_kernel<<<g, 256, 0, stream>>>(xc, W_x, xpart);
    xproj_reduce_kernel<<<(NROWS * 96 / 4) / 256, 256, 0, stream>>>(xpart, dbl);
  }
  // 4. dt_proj + fused softplus -> dt
  {
    dim3 g(D_INNER / 128, NROWS / 128);
    dtproj_kernel<<<g, 256, 0, stream>>>(dbl, W_dt, b_dt, dt);
  }
  // 5. chunked selective scan (chain-per-lane)
  {
    dim3 gAC(D_INNER / 256, NCHUNK, BATCH);
    scanA_kernel<<<gAC, 256, 0, stream>>>(dt, xc, dbl, A_log, Pbuf, Lbuf);
    scanB_kernel<<<(BATCH * D_INNER * 16) / 256, 256, 0, stream>>>(Pbuf, Lbuf, xz);
    scanC_kernel<<<gAC, 256, 0, stream>>>(dt, xc, dbl, A_log, Dp, xz, yg);
  }
  // 6. RMSNorm -> bf16 ygb
  rms_bf16_kernel<<<NROWS, 256, 0, stream>>>(yg, rms_w, ygb);
  // 6b. convert W_out -> bf16
  f32_to_bf16_kernel<<<(D_MODEL * D_INNER / 4 + 255) / 256, 256, 0, stream>>>(W_out, W_out_b, D_MODEL * D_INNER / 4);
  // 7. out_proj: split-K=2 partials (xc region) + reduce -> out
  {
    dim3 g(D_MODEL / 64, NROWS / 64, 2);
    gemm_wave_out<<<g, 64, 0, stream>>>(ygb, D_INNER, W_out_b, D_INNER, opart, D_MODEL, D_INNER / 2);
    splitk2_reduce_kernel<<<(NROWS * D_MODEL / 4) / 256, 256, 0, stream>>>(opart, out);
  }
}

// Round 12
// 293.691 us; speedup vs baseline: 1.2688x; 1.2688x over previous
//
#include <hip/hip_runtime.h>
#include <hip/hip_bf16.h>

// ---------------- problem dims ----------------
#define D_MODEL 1024
#define D_INNER 2048
#define D_STATE 16
#define D_CONVK 4
#define DT_RANK 64
#define BATCH   2
#define SEQ     1024
#define NROWS   (BATCH*SEQ)          // 2048 rows (b*s flattened)

// scan chunking (chain-per-lane layout)
#define NCHUNK  32
#define CHUNK   (SEQ/NCHUNK)         // 32

// ---------------- ws layout (float elements) ----------------
#define XZ_OFF  0
#define XZ_SZ   (NROWS*2*D_INNER)
#define XC_OFF  (XZ_OFF + XZ_SZ)
#define XC_SZ   (NROWS*D_INNER)
#define DBL_OFF (XC_OFF + XC_SZ)
#define DBL_SZ  (NROWS*96)
#define DT_OFF  (DBL_OFF + DBL_SZ)
#define DT_SZ   (NROWS*D_INNER)
#define YG_OFF  (DT_OFF + DT_SZ)
#define YG_SZ   (NROWS*D_INNER)
// total = 21,168,128 floats = 84.7 MB (unchanged)
//
// Region reuse timeline (write-before-read everywhere):
//  yg region: [t0] xb bf16 | W_in_b bf16 (dead after in_proj)
//             [scanA/B] Pbuf | Lbuf (dead after scanB) -> [scanC] yg f32
//  dt region: [xproj] partials -> [dtproj] dt f32
//             [after scanC] ygb bf16 | W_out_b bf16
//  xc region: conv output; dead after scanC -> out_proj split-K partials (2x2M)
//  xz x_in half: dead after conv -> HST

// HST packed into the x_in half of xz (row stride 4096)
__device__ __forceinline__ float& plh_at(float* xz, int i) {
  return xz[((size_t)(i >> 11)) * (2 * D_INNER) + (i & (D_INNER - 1))];
}

typedef unsigned short ushort_t;
typedef __attribute__((ext_vector_type(8))) short  bf16x8;
typedef __attribute__((ext_vector_type(4))) float  f32x4;

__device__ __forceinline__ ushort_t f2bf(float f) {
  unsigned u = __float_as_uint(f);
  unsigned r = (u + 0x7fffu + ((u >> 16) & 1u)) >> 16;
  return (ushort_t)r;
}

__device__ __forceinline__ void gld_lds16(const ushort_t* g, ushort_t* l) {
  __builtin_amdgcn_global_load_lds(
      (const __attribute__((address_space(1))) unsigned int*)(const void*)g,
      (__attribute__((address_space(3))) unsigned int*)(void*)l,
      16, 0, 0);
}

// ======================================================================
// f32 -> bf16 convert
// ======================================================================
__global__ __launch_bounds__(256) void f32_to_bf16_kernel(
    const float* __restrict__ src, ushort_t* __restrict__ dst, int n4)
{
  const int i = blockIdx.x * 256 + threadIdx.x;
  if (i >= n4) return;
  const float4 v = ((const float4*)src)[i];
  ushort4 o;
  o.x = f2bf(v.x); o.y = f2bf(v.y); o.z = f2bf(v.z); o.w = f2bf(v.w);
  ((ushort4*)dst)[i] = o;
}

// ======================================================================
// Single-wave bf16 MFMA GEMM (r10 form — pipelining REVERTED, it cost +23%).
// One 64-thread wave per block owns a 64x64 tile (4x4 frags of 16x16x32).
// BK=32, global_load_lds staging with bank-conflict swizzle (linear LDS
// dest, pre-swizzled global source; read slot lk^((lm>>1)&3) -> 2-way).
// Independent waves: no inter-wave lock-step; drains hidden by TLP.
// Optional split-K via blockIdx.z: C slice z at C + z*(gridDim.y*64)*ldc.
// Two named instantiations so rocprof attributes in/out separately.
// ======================================================================
#define DEF_GEMM_WAVE(NAME)                                                    \
__global__ __launch_bounds__(64, 4) void NAME(                                 \
    const ushort_t* __restrict__ A, int lda,                                   \
    const ushort_t* __restrict__ B, int ldb,                                   \
    float* __restrict__ C, int ldc, int klen)                                  \
{                                                                              \
  __shared__ __attribute__((aligned(16))) ushort_t As[64 * 32];                \
  __shared__ __attribute__((aligned(16))) ushort_t Bs[64 * 32];                \
                                                                               \
  const int l  = threadIdx.x;                                                  \
  const int lm = l & 15;                                                       \
  const int lk = l >> 4;                                                       \
  const int bn = blockIdx.x * 64;                                              \
  const int bm = blockIdx.y * 64;                                              \
  const int kbase = blockIdx.z * klen;                                         \
  float* Cz = C + (size_t)blockIdx.z * (size_t)gridDim.y * 64 * ldc;           \
                                                                               \
  const int srow  = l >> 2;                                                    \
  const int scol  = ((l & 3) ^ ((l >> 3) & 3)) * 8;                            \
  const int rslot = (lk ^ ((lm >> 1) & 3)) * 8;                                \
                                                                               \
  f32x4 acc[4][4];                                                             \
  _Pragma("unroll")                                                            \
  for (int i = 0; i < 4; ++i)                                                  \
    _Pragma("unroll")                                                          \
    for (int j = 0; j < 4; ++j) acc[i][j] = (f32x4){0.f, 0.f, 0.f, 0.f};       \
                                                                               \
  for (int k0 = kbase; k0 < kbase + klen; k0 += 32) {                          \
    __syncthreads();                                                           \
    _Pragma("unroll")                                                          \
    for (int i = 0; i < 4; ++i)                                                \
      gld_lds16(A + (size_t)(bm + i * 16 + srow) * lda + k0 + scol,            \
                &As[i * 16 * 32]);                                             \
    _Pragma("unroll")                                                          \
    for (int i = 0; i < 4; ++i)                                                \
      gld_lds16(B + (size_t)(bn + i * 16 + srow) * ldb + k0 + scol,            \
                &Bs[i * 16 * 32]);                                             \
    __syncthreads();                                                           \
                                                                               \
    bf16x8 af[4], bf[4];                                                       \
    _Pragma("unroll")                                                          \
    for (int mi = 0; mi < 4; ++mi)                                             \
      af[mi] = *(const bf16x8*)&As[(mi * 16 + lm) * 32 + rslot];               \
    _Pragma("unroll")                                                          \
    for (int ni = 0; ni < 4; ++ni)                                             \
      bf[ni] = *(const bf16x8*)&Bs[(ni * 16 + lm) * 32 + rslot];               \
    _Pragma("unroll")                                                          \
    for (int mi = 0; mi < 4; ++mi)                                             \
      _Pragma("unroll")                                                        \
      for (int ni = 0; ni < 4; ++ni)                                           \
        acc[mi][ni] = __builtin_amdgcn_mfma_f32_16x16x32_bf16(                 \
            af[mi], bf[ni], acc[mi][ni], 0, 0, 0);                             \
  }                                                                            \
                                                                               \
  _Pragma("unroll")                                                            \
  for (int mi = 0; mi < 4; ++mi) {                                             \
    _Pragma("unroll")                                                          \
    for (int ni = 0; ni < 4; ++ni) {                                           \
      const f32x4 v = acc[mi][ni];                                             \
      const int row0 = bm + mi * 16 + lk * 4;                                  \
      const int col  = bn + ni * 16 + lm;                                      \
      _Pragma("unroll")                                                        \
      for (int r = 0; r < 4; ++r)                                              \
        Cz[(size_t)(row0 + r) * ldc + col] = v[r];                             \
    }                                                                          \
  }                                                                            \
}

DEF_GEMM_WAVE(gemm_wave_in)
DEF_GEMM_WAVE(gemm_wave_out)

// out = p0 + p1 over NROWS*D_MODEL (split-K=2 reduce for out_proj)
__global__ __launch_bounds__(256) void splitk2_reduce_kernel(
    const float* __restrict__ part, float* __restrict__ out)
{
  const int i = blockIdx.x * 256 + threadIdx.x;   // over NROWS*D_MODEL/4
  const float4 a = ((const float4*)part)[i];
  const float4 b = ((const float4*)part)[i + (NROWS * D_MODEL / 4)];
  ((float4*)out)[i] = make_float4(a.x + b.x, a.y + b.y, a.z + b.z, a.w + b.w);
}

// ======================================================================
// x_proj split-K, dense partials (no atomics)
// ======================================================================
#define XP_NS 16
#define XP_KC (D_INNER / XP_NS)   // 128
#define XP_BK 16

__global__ __launch_bounds__(256) void xproj_part_kernel(
    const float* __restrict__ A,   // xc [2048][2048]
    const float* __restrict__ B,   // W_x [96][2048]
    float* __restrict__ part)      // [16][2048][96]
{
  __shared__ float As[XP_BK][64 + 4];
  __shared__ float Bs[XP_BK][96 + 4];

  const int tid = threadIdx.x;
  const int bm = blockIdx.x * 64;
  const int kbase = blockIdx.y * XP_KC;
  const int tm = tid >> 4;
  const int tn = tid & 15;

  float acc[4][6];
#pragma unroll
  for (int i = 0; i < 4; ++i)
#pragma unroll
    for (int j = 0; j < 6; ++j) acc[i][j] = 0.f;

  for (int k0 = kbase; k0 < kbase + XP_KC; k0 += XP_BK) {
    {
      const int row = tid >> 2, kc = (tid & 3) * 4;
      const float4 v = *(const float4*)(A + (size_t)(bm + row) * D_INNER + k0 + kc);
      As[kc + 0][row] = v.x; As[kc + 1][row] = v.y;
      As[kc + 2][row] = v.z; As[kc + 3][row] = v.w;
    }
    for (int idx = tid; idx < 96 * 4; idx += 256) {
      const int row = idx >> 2, kc = (idx & 3) * 4;
      const float4 v = *(const float4*)(B + (size_t)row * D_INNER + k0 + kc);
      Bs[kc + 0][row] = v.x; Bs[kc + 1][row] = v.y;
      Bs[kc + 2][row] = v.z; Bs[kc + 3][row] = v.w;
    }
    __syncthreads();

#pragma unroll
    for (int kk = 0; kk < XP_BK; ++kk) {
      float a[4], b[6];
#pragma unroll
      for (int i = 0; i < 4; ++i) a[i] = As[kk][tm * 4 + i];
#pragma unroll
      for (int j = 0; j < 6; ++j) b[j] = Bs[kk][tn * 6 + j];
#pragma unroll
      for (int i = 0; i < 4; ++i)
#pragma unroll
        for (int j = 0; j < 6; ++j)
          acc[i][j] = fmaf(a[i], b[j], acc[i][j]);
    }
    __syncthreads();
  }

  float* p = part + (size_t)blockIdx.y * (NROWS * 96);
#pragma unroll
  for (int i = 0; i < 4; ++i) {
    const int gm = bm + tm * 4 + i;
#pragma unroll
    for (int j = 0; j < 6; ++j)
      p[(size_t)gm * 96 + tn * 6 + j] = acc[i][j];
  }
}

__global__ __launch_bounds__(256) void xproj_reduce_kernel(
    const float* __restrict__ part, float* __restrict__ dbl)
{
  const int i = blockIdx.x * 256 + threadIdx.x;
  const float4* p4 = (const float4*)part;
  float4 s = p4[i];
#pragma unroll
  for (int ks = 1; ks < XP_NS; ++ks) {
    const float4 v = p4[(size_t)ks * (NROWS * 96 / 4) + i];
    s.x += v.x; s.y += v.y; s.z += v.z; s.w += v.w;
  }
  ((float4*)dbl)[i] = s;
}

// ======================================================================
// dt_proj + fused softplus — occupancy-fixed version.
// K=64 staged ONCE (single barrier). BM=64 x BN=128, 256 threads,
// 4x8 microtile/thread. Grid (16,32) = 512 blocks; LDS ~51 KB -> 3
// blocks/CU (12 waves/CU) vs old 1 block/CU latency-bound structure.
// ======================================================================
#define DTP_BM 64
#define DTP_BN 128

__global__ __launch_bounds__(256) void dtproj_kernel(
    const float* __restrict__ A,    // dbl [2048][96] (cols 0..63 used)
    const float* __restrict__ B,    // W_dt [2048][64]
    const float* __restrict__ b_dt,
    float* __restrict__ C)          // dt [2048][2048]
{
  __shared__ float As[DT_RANK][DTP_BM + 4];   // [64][68]
  __shared__ float Bs[DT_RANK][DTP_BN + 4];   // [64][132]

  const int tid = threadIdx.x;
  const int bm = blockIdx.y * DTP_BM;
  const int bn = blockIdx.x * DTP_BN;
  const int tm = tid >> 4;   // 0..15 -> 4 rows each
  const int tn = tid & 15;   // 0..15 -> 8 cols each

  // stage A: 64 rows x 64 k (transposed to [k][row])
  for (int idx = tid; idx < DTP_BM * 16; idx += 256) {
    const int r = idx >> 4, kc = (idx & 15) * 4;
    const float4 v = *(const float4*)(A + (size_t)(bm + r) * 96 + kc);
    As[kc + 0][r] = v.x; As[kc + 1][r] = v.y;
    As[kc + 2][r] = v.z; As[kc + 3][r] = v.w;
  }
  // stage B: 128 rows x 64 k
  for (int idx = tid; idx < DTP_BN * 16; idx += 256) {
    const int r = idx >> 4, kc = (idx & 15) * 4;
    const float4 v = *(const float4*)(B + (size_t)(bn + r) * DT_RANK + kc);
    Bs[kc + 0][r] = v.x; Bs[kc + 1][r] = v.y;
    Bs[kc + 2][r] = v.z; Bs[kc + 3][r] = v.w;
  }
  __syncthreads();

  float acc[4][8];
#pragma unroll
  for (int i = 0; i < 4; ++i)
#pragma unroll
    for (int j = 0; j < 8; ++j) acc[i][j] = 0.f;

  for (int kk = 0; kk < DT_RANK; ++kk) {
    const float4 a0 = *(const float4*)&As[kk][tm * 4];
    const float4 b0 = *(const float4*)&Bs[kk][tn * 8];
    const float4 b1 = *(const float4*)&Bs[kk][tn * 8 + 4];
    const float a[4] = {a0.x, a0.y, a0.z, a0.w};
    const float b[8] = {b0.x, b0.y, b0.z, b0.w, b1.x, b1.y, b1.z, b1.w};
#pragma unroll
    for (int i = 0; i < 4; ++i)
#pragma unroll
      for (int j = 0; j < 8; ++j)
        acc[i][j] = fmaf(a[i], b[j], acc[i][j]);
  }

  const int gn0 = bn + tn * 8;
  float bv[8];
#pragma unroll
  for (int j = 0; j < 8; ++j) bv[j] = b_dt[gn0 + j];
#pragma unroll
  for (int i = 0; i < 4; ++i) {
    const int gm = bm + tm * 4 + i;
    float o[8];
#pragma unroll
    for (int j = 0; j < 8; ++j) {
      const float v = acc[i][j] + bv[j];
      const float sp = (v > 20.f) ? v : log1pf(__expf(v));
      o[j] = sp + 1e-4f;
    }
    *(float4*)(C + (size_t)gm * D_INNER + gn0)     = make_float4(o[0], o[1], o[2], o[3]);
    *(float4*)(C + (size_t)gm * D_INNER + gn0 + 4) = make_float4(o[4], o[5], o[6], o[7]);
  }
}

// ======================================================================
// depthwise causal conv1d + SiLU
// ======================================================================
__global__ __launch_bounds__(256) void conv_silu_kernel(
    const float* __restrict__ xz, const float* __restrict__ Wc,
    const float* __restrict__ bc, float* __restrict__ xc)
{
  const int idx = blockIdx.x * 256 + threadIdx.x;
  const int d = idx & (D_INNER - 1);
  const int m = idx >> 11;
  const int s = m & (SEQ - 1);
  const int mb = m - s;
  float acc = bc[d];
#pragma unroll
  for (int k = 0; k < D_CONVK; ++k) {
    const int t = s + k - (D_CONVK - 1);
    if (t >= 0)
      acc = fmaf(Wc[d * D_CONVK + k], xz[(size_t)(mb + t) * (2 * D_INNER) + d], acc);
  }
  xc[idx] = acc / (1.f + __expf(-acc));
}

// ======================================================================
// scan pass A (chain-per-lane)
// ======================================================================
__global__ __launch_bounds__(256) void scanA_kernel(
    const float* __restrict__ dtv, const float* __restrict__ xc,
    const float* __restrict__ dbl, const float* __restrict__ A_log,
    float* __restrict__ Pbuf, float* __restrict__ Lbuf)
{
  __shared__ float sB[CHUNK][16];

  const int tid = threadIdx.x;
  const int d = blockIdx.x * 256 + tid;
  const int chunk = blockIdx.y;
  const int b = blockIdx.z;
  const int rowbase = b * SEQ + chunk * CHUNK;

  for (int idx = tid; idx < CHUNK * 16; idx += 256) {
    const int i = idx >> 4, n = idx & 15;
    sB[i][n] = dbl[(size_t)(rowbase + i) * 96 + 64 + n];
  }

  float A_d[16];
#pragma unroll
  for (int j = 0; j < 4; ++j) {
    const float4 va = *(const float4*)&A_log[d * D_STATE + j * 4];
    A_d[j * 4 + 0] = -__expf(va.x);
    A_d[j * 4 + 1] = -__expf(va.y);
    A_d[j * 4 + 2] = -__expf(va.z);
    A_d[j * 4 + 3] = -__expf(va.w);
  }
  __syncthreads();

  float h[16], P[16];
#pragma unroll
  for (int n = 0; n < 16; ++n) { h[n] = 0.f; P[n] = 1.f; }

  for (int i = 0; i < CHUNK; ++i) {
    const size_t off = (size_t)(rowbase + i) * D_INNER + d;
    const float dt_v = dtv[off];
    const float dtxc = dt_v * xc[off];
    const float4 B0 = *(const float4*)&sB[i][0];
    const float4 B1 = *(const float4*)&sB[i][4];
    const float4 B2 = *(const float4*)&sB[i][8];
    const float4 B3 = *(const float4*)&sB[i][12];
    const float Bv[16] = {B0.x,B0.y,B0.z,B0.w, B1.x,B1.y,B1.z,B1.w,
                          B2.x,B2.y,B2.z,B2.w, B3.x,B3.y,B3.z,B3.w};
#pragma unroll
    for (int n = 0; n < 16; ++n) {
      float t = dt_v * A_d[n];
      t = fminf(fmaxf(t, -10.f), 10.f);
      const float dA = __expf(t);
      h[n] = fmaf(dA, h[n], dtxc * Bv[n]);
      P[n] *= dA;
    }
  }

  const size_t base = ((size_t)(chunk * BATCH + b) * 16) * D_INNER + d;
#pragma unroll
  for (int n = 0; n < 16; ++n) {
    Pbuf[base + (size_t)n * D_INNER] = P[n];
    Lbuf[base + (size_t)n * D_INNER] = h[n];
  }
}

// ======================================================================
// scan pass B
// ======================================================================
__global__ __launch_bounds__(256) void scanB_kernel(
    const float* __restrict__ Pbuf, const float* __restrict__ Lbuf,
    float* __restrict__ xzp)
{
  const int t = blockIdx.x * 256 + threadIdx.x;
  const int d = t & (D_INNER - 1);
  const int n = (t >> 11) & 15;
  const int b = t >> 15;
  float hs = 0.f;
#pragma unroll
  for (int c = 0; c < NCHUNK; ++c) {
    const int idx = ((c * BATCH + b) * 16 + n) * D_INNER + d;
    plh_at(xzp, idx) = hs;
    hs = fmaf(Pbuf[idx], hs, Lbuf[idx]);
  }
}

// ======================================================================
// scan pass C (chain-per-lane)
// ======================================================================
__global__ __launch_bounds__(256) void scanC_kernel(
    const float* __restrict__ dtv, const float* __restrict__ xc,
    const float* __restrict__ dbl, const float* __restrict__ A_log,
    const float* __restrict__ Dp,  float* __restrict__ xzp,
    float* __restrict__ yg)
{
  __shared__ float sBC[CHUNK][32];

  const int tid = threadIdx.x;
  const int d = blockIdx.x * 256 + tid;
  const int chunk = blockIdx.y;
  const int b = blockIdx.z;
  const int rowbase = b * SEQ + chunk * CHUNK;

  for (int idx = tid; idx < CHUNK * 32; idx += 256) {
    const int i = idx >> 5, j = idx & 31;
    sBC[i][j] = dbl[(size_t)(rowbase + i) * 96 + 64 + j];
  }

  float A_d[16];
#pragma unroll
  for (int j = 0; j < 4; ++j) {
    const float4 va = *(const float4*)&A_log[d * D_STATE + j * 4];
    A_d[j * 4 + 0] = -__expf(va.x);
    A_d[j * 4 + 1] = -__expf(va.y);
    A_d[j * 4 + 2] = -__expf(va.z);
    A_d[j * 4 + 3] = -__expf(va.w);
  }
  const float Dd = Dp[d];
  __syncthreads();

  float h[16];
  {
    const int hbase = ((chunk * BATCH + b) * 16) * D_INNER + d;
#pragma unroll
    for (int n = 0; n < 16; ++n) h[n] = plh_at(xzp, hbase + n * D_INNER);
  }

  for (int i = 0; i < CHUNK; ++i) {
    const int m = rowbase + i;
    const size_t off = (size_t)m * D_INNER + d;
    const float dt_v = dtv[off];
    const float xc_v = xc[off];
    const float dtxc = dt_v * xc_v;
    const float4 B0 = *(const float4*)&sBC[i][0];
    const float4 B1 = *(const float4*)&sBC[i][4];
    const float4 B2 = *(const float4*)&sBC[i][8];
    const float4 B3 = *(const float4*)&sBC[i][12];
    const float4 C0 = *(const float4*)&sBC[i][16];
    const float4 C1 = *(const float4*)&sBC[i][20];
    const float4 C2 = *(const float4*)&sBC[i][24];
    const float4 C3 = *(const float4*)&sBC[i][28];
    const float Bv[16] = {B0.x,B0.y,B0.z,B0.w, B1.x,B1.y,B1.z,B1.w,
                          B2.x,B2.y,B2.z,B2.w, B3.x,B3.y,B3.z,B3.w};
    const float Cv[16] = {C0.x,C0.y,C0.z,C0.w, C1.x,C1.y,C1.z,C1.w,
                          C2.x,C2.y,C2.z,C2.w, C3.x,C3.y,C3.z,C3.w};
    float y = 0.f;
#pragma unroll
    for (int n = 0; n < 16; ++n) {
      float t = dt_v * A_d[n];
      t = fminf(fmaxf(t, -10.f), 10.f);
      const float dA = __expf(t);
      h[n] = fmaf(dA, h[n], dtxc * Bv[n]);
      y = fmaf(h[n], Cv[n], y);
    }
    const float zv = xzp[(size_t)m * (2 * D_INNER) + D_INNER + d];
    const float sil = zv / (1.f + __expf(-zv));
    yg[off] = (y + xc_v * Dd) * sil;
  }
}

// ======================================================================
// RMSNorm: read yg f32, write bf16
// ======================================================================
__global__ __launch_bounds__(256) void rms_bf16_kernel(
    const float* __restrict__ yg, const float* __restrict__ rms_w,
    ushort_t* __restrict__ ygb)
{
  const int m = blockIdx.x;
  const float* row = yg + (size_t)m * D_INNER;
  const int e0 = threadIdx.x * 8;
  float4 v0 = *(const float4*)&row[e0];
  float4 v1 = *(const float4*)&row[e0 + 4];
  float ss = v0.x*v0.x + v0.y*v0.y + v0.z*v0.z + v0.w*v0.w
           + v1.x*v1.x + v1.y*v1.y + v1.z*v1.z + v1.w*v1.w;
#pragma unroll
  for (int off = 32; off > 0; off >>= 1) ss += __shfl_down(ss, off);
  __shared__ float wsum[4];
  const int lane = threadIdx.x & 63, wid = threadIdx.x >> 6;
  if (lane == 0) wsum[wid] = ss;
  __syncthreads();
  const float total = wsum[0] + wsum[1] + wsum[2] + wsum[3];
  const float scale = rsqrtf(total / (float)D_INNER + 1e-6f);
  const float4 w0 = *(const float4*)&rms_w[e0];
  const float4 w1 = *(const float4*)&rms_w[e0 + 4];
  ushort4 o0, o1;
  o0.x = f2bf(v0.x * scale * w0.x); o0.y = f2bf(v0.y * scale * w0.y);
  o0.z = f2bf(v0.z * scale * w0.z); o0.w = f2bf(v0.w * scale * w0.w);
  o1.x = f2bf(v1.x * scale * w1.x); o1.y = f2bf(v1.y * scale * w1.y);
  o1.z = f2bf(v1.z * scale * w1.z); o1.w = f2bf(v1.w * scale * w1.w);
  *(ushort4*)&ygb[(size_t)m * D_INNER + e0]     = o0;
  *(ushort4*)&ygb[(size_t)m * D_INNER + e0 + 4] = o1;
}

// ======================================================================
extern "C" void kernel_launch(void* const* d_in, const int* in_sizes, int n_in,
                              void* d_out, int out_size, void* d_ws, size_t ws_size,
                              hipStream_t stream) {
  const float* x      = (const float*)d_in[0];
  const float* W_in   = (const float*)d_in[1];
  const float* W_conv = (const float*)d_in[2];
  const float* b_conv = (const float*)d_in[3];
  const float* W_x    = (const float*)d_in[4];
  const float* W_dt   = (const float*)d_in[5];
  const float* b_dt   = (const float*)d_in[6];
  const float* A_log  = (const float*)d_in[7];
  const float* Dp     = (const float*)d_in[8];
  const float* rms_w  = (const float*)d_in[9];
  const float* W_out  = (const float*)d_in[10];
  float* out = (float*)d_out;
  float* ws  = (float*)d_ws;

  float* xz  = ws + XZ_OFF;
  float* xc  = ws + XC_OFF;
  float* dbl = ws + DBL_OFF;
  float* dt  = ws + DT_OFF;
  float* yg  = ws + YG_OFF;

  // region-reuse aliases
  ushort_t* xb      = (ushort_t*)(ws + YG_OFF);                    // bf16 x
  ushort_t* W_in_b  = (ushort_t*)(ws + YG_OFF + 1024 * 1024);      // bf16 W_in
  float*    xpart   = ws + DT_OFF;                                 // xproj partials
  float*    Pbuf    = ws + YG_OFF;                                 // scan P
  float*    Lbuf    = ws + YG_OFF + 2 * 1024 * 1024;               // scan L
  ushort_t* ygb     = (ushort_t*)(ws + DT_OFF);                    // bf16 y
  ushort_t* W_out_b = (ushort_t*)(ws + DT_OFF + 2 * 1024 * 1024);  // bf16 W_out
  float*    opart   = ws + XC_OFF;                                 // out_proj partials (2x2M, xc dead)

  // 0. convert x, W_in to bf16
  f32_to_bf16_kernel<<<(NROWS * D_MODEL / 4 + 255) / 256, 256, 0, stream>>>(x, xb, NROWS * D_MODEL / 4);
  f32_to_bf16_kernel<<<(2 * D_INNER * D_MODEL / 4 + 255) / 256, 256, 0, stream>>>(W_in, W_in_b, 2 * D_INNER * D_MODEL / 4);

  // 1. in_proj: xz = xb @ W_in_b^T (single-wave MFMA, 2048 blocks)
  {
    dim3 g((2 * D_INNER) / 64, NROWS / 64, 1);
    gemm_wave_in<<<g, 64, 0, stream>>>(xb, D_MODEL, W_in_b, D_MODEL, xz, 2 * D_INNER, D_MODEL);
  }
  // 2. conv + silu -> xc
  conv_silu_kernel<<<(NROWS * D_INNER) / 256, 256, 0, stream>>>(xz, W_conv, b_conv, xc);
  // 3. x_proj: dense split-K partials + reduce
  {
    dim3 g(NROWS / 64, XP_NS);
    xproj_part_kernel<<<g, 256, 0, stream>>>(xc, W_x, xpart);
    xproj_reduce_kernel<<<(NROWS * 96 / 4) / 256, 256, 0, stream>>>(xpart, dbl);
  }
  // 4. dt_proj + fused softplus -> dt (single-stage K=64, 512 blocks)
  {
    dim3 g(D_INNER / DTP_BN, NROWS / DTP_BM);
    dtproj_kernel<<<g, 256, 0, stream>>>(dbl, W_dt, b_dt, dt);
  }
  // 5. chunked selective scan (chain-per-lane)
  {
    dim3 gAC(D_INNER / 256, NCHUNK, BATCH);
    scanA_kernel<<<gAC, 256, 0, stream>>>(dt, xc, dbl, A_log, Pbuf, Lbuf);
    scanB_kernel<<<(BATCH * D_INNER * 16) / 256, 256, 0, stream>>>(Pbuf, Lbuf, xz);
    scanC_kernel<<<gAC, 256, 0, stream>>>(dt, xc, dbl, A_log, Dp, xz, yg);
  }
  // 6. RMSNorm -> bf16 ygb
  rms_bf16_kernel<<<NROWS, 256, 0, stream>>>(yg, rms_w, ygb);
  // 6b. convert W_out -> bf16
  f32_to_bf16_kernel<<<(D_MODEL * D_INNER / 4 + 255) / 256, 256, 0, stream>>>(W_out, W_out_b, D_MODEL * D_INNER / 4);
  // 7. out_proj: split-K=2 partials (xc region) + reduce -> out
  {
    dim3 g(D_MODEL / 64, NROWS / 64, 2);
    gemm_wave_out<<<g, 64, 0, stream>>>(ygb, D_INNER, W_out_b, D_INNER, opart, D_MODEL, D_INNER / 2);
    splitk2_reduce_kernel<<<(NROWS * D_MODEL / 4) / 256, 256, 0, stream>>>(opart, out);
  }
}